// Round 7
// baseline (130.217 us; speedup 1.0000x reference)
//
#include <hip/hip_runtime.h>
#include <hip/hip_cooperative_groups.h>
#include <math.h>

namespace cg = cooperative_groups;

// Problem constants (match reference setup_inputs)
#define NH 8
#define DIM 128
#define KD 16
#define NB 16
#define NG 501
#define NPK 250
#define QROWS 512
// nf * log2(e) = 0.25 * 1.4426950408889634
#define QSCALE 0.36067376022224085f

typedef unsigned short ushort_t;
typedef __attribute__((ext_vector_type(8))) short short8v;
typedef __attribute__((ext_vector_type(4))) short short4v;
typedef __attribute__((ext_vector_type(2))) short short2v;
typedef __attribute__((ext_vector_type(4))) float f32x4;

#define MFMA(a, b, c) __builtin_amdgcn_mfma_f32_16x16x32_bf16(a, b, c, 0, 0, 0)

static __device__ __forceinline__ ushort_t f2bf(float x) {  // RNE, finite only
  union { float f; unsigned u; } v; v.f = x;
  unsigned r = v.u + 0x7FFFu + ((v.u >> 16) & 1u);
  return (ushort_t)(r >> 16);
}
static __device__ __forceinline__ float bf2f(ushort_t h) {
  union { unsigned u; float f; } v; v.u = ((unsigned)h) << 16;
  return v.f;
}
static __device__ __forceinline__ unsigned cvtpk(float lo, float hi) {
  unsigned r;
  asm("v_cvt_pk_bf16_f32 %0, %1, %2" : "=v"(r) : "v"(lo), "v"(hi));
  return r;
}

struct FArgs {
  const float *q, *wq, *wk, *wv, *w1, *w2, *w3, *w4, *wo;
  float* out;
  char* ws;
};

// ws layout (1 MB units)
//  0: qh_g [16][512][128] (2MB) -- aliased as HdH after proj
//  2: ql_g (2MB)                -- aliased as HdL
//  4: QcH [128hb][512][16]  6: QcL   8: QPH  10: QPL  12: QDH  14: QDL
// 16: Kb  [128hb][512][32] (4MB)
// 20: Vt  [128hb][16][512] (2MB)
// 22: Wsh frag-layout (229KB)  23: Wsl
// 24: Wosh (256KB)             25: Wosl

// ===========================================================================
// Fused cooperative kernel: 256 blocks x 512 threads (1 block/CU guaranteed).
// ===========================================================================
__global__ __launch_bounds__(512, 2) void fused_kernel(FArgs a)
{
  __shared__ __align__(16) ushort_t Klds[16384];   // [ch32][lcol16][lh4][8]
  __shared__ __align__(16) ushort_t Vlds[8192];    // [grp16][lh4][v16][8]

  char* wsb = a.ws;
  ushort_t* qh_g = (ushort_t*)(wsb + (0u  << 20));
  ushort_t* ql_g = (ushort_t*)(wsb + (2u  << 20));
  ushort_t* QcH  = (ushort_t*)(wsb + (4u  << 20));
  ushort_t* QcL  = (ushort_t*)(wsb + (6u  << 20));
  ushort_t* QPH  = (ushort_t*)(wsb + (8u  << 20));
  ushort_t* QPL  = (ushort_t*)(wsb + (10u << 20));
  ushort_t* QDH  = (ushort_t*)(wsb + (12u << 20));
  ushort_t* QDL  = (ushort_t*)(wsb + (14u << 20));
  ushort_t* Kb   = (ushort_t*)(wsb + (16u << 20));
  ushort_t* Vt   = (ushort_t*)(wsb + (20u << 20));
  ushort_t* Wsh  = (ushort_t*)(wsb + (22u << 20));
  ushort_t* Wsl  = (ushort_t*)(wsb + (23u << 20));
  ushort_t* Wosh = (ushort_t*)(wsb + (24u << 20));
  ushort_t* Wosl = (ushort_t*)(wsb + (25u << 20));
  ushort_t* HdH  = qh_g;
  ushort_t* HdL  = ql_g;

  cg::grid_group grid = cg::this_grid();
  const int tid = threadIdx.x;
  const int wid = tid >> 6, lane = tid & 63;

  // ============================ Phase 0: convert =========================
  {
    const int idx = blockIdx.x * 512 + tid;   // 0..131071
    {
      int b = idx >> 13, r = (idx >> 4) & 511, c8 = (idx & 15) * 8;
      short8v h8 = {0,0,0,0,0,0,0,0}, l8 = {0,0,0,0,0,0,0,0};
      if (r < NG) {
        const float* src = &a.q[(size_t)(b * NG + r) * DIM + c8];
        float4 x = *(const float4*)src, y = *(const float4*)(src + 4);
        float vals[8] = {x.x, x.y, x.z, x.w, y.x, y.y, y.z, y.w};
#pragma unroll
        for (int j = 0; j < 8; ++j) {
          ushort_t hi = f2bf(vals[j]);
          h8[j] = (short)hi;
          l8[j] = (short)f2bf(vals[j] - bf2f(hi));
        }
      }
      size_t off = (size_t)(b * 512 + r) * DIM + c8;
      *(short8v*)&qh_g[off] = h8;
      *(short8v*)&ql_g[off] = l8;
    }
    if (idx < 114688) {   // 7 W's -> frag layout hi/lo
      int p = idx >> 14, rem = idx & 16383;
      int h = rem >> 11, r2 = rem & 2047;
      int d = r2 >> 4, lrow = r2 & 15;
      const float* W = (p == 0) ? a.wq : (p == 1) ? a.wk : (p == 2) ? a.wv :
                       (p == 3) ? a.w1 : (p == 4) ? a.w2 : (p == 5) ? a.w3 : a.w4;
      float v = W[h * 2048 + d * 16 + lrow];
      ushort_t hi = f2bf(v), lo = f2bf(v - bf2f(hi));
      int c = d >> 5, kg = (d >> 3) & 3, j = d & 7;
      size_t dst = ((((size_t)(p * 8 + h) * 4 + c) * 4 + kg) * 16 + lrow) * 8 + j;
      Wsh[dst] = hi; Wsl[dst] = lo;
    }
    if (idx < 16384) {    // Wout -> frag layout hi/lo
      int hkd = idx >> 7, e = idx & 127;
      float v = a.wo[(size_t)hkd * 128 + e];
      ushort_t hi = f2bf(v), lo = f2bf(v - bf2f(hi));
      int c = hkd >> 5, kg = (hkd >> 3) & 3, j = hkd & 7;
      size_t dst = (((size_t)c * 4 + kg) * 128 + e) * 8 + j;
      Wosh[dst] = hi; Wosl[dst] = lo;
    }
  }
  grid.sync();

  // ============================ Phase 1: proj ============================
  {
    const int lrow = lane & 15, kgrp = lane >> 4;
    const int sub = wid >> 2, w4 = wid & 3;
    const int p0 = w4 * 2;
    const int p1 = (w4 < 3) ? w4 * 2 + 1 : -1;
    const f32x4 zero4 = {0.f, 0.f, 0.f, 0.f};

#pragma unroll 1
    for (int u = 0; u < 2; ++u) {
      const int unit = (blockIdx.x * 2 + sub) * 2 + u;   // 0..1023
      const int rc = unit & 7, b = (unit >> 3) & 15, h = unit >> 7;
      const size_t hb = (size_t)h * NB + b;

      short8v whf[2][4], wlf[2][4];
#pragma unroll
      for (int slot = 0; slot < 2; ++slot) {
        int p = slot ? p1 : p0;
        if (p < 0) continue;
#pragma unroll
        for (int c = 0; c < 4; ++c) {
          size_t off = ((((size_t)(p * 8 + h) * 4 + c) * 4 + kgrp) * 16 + lrow) * 8;
          whf[slot][c] = *(const short8v*)&Wsh[off];
          wlf[slot][c] = *(const short8v*)&Wsl[off];
        }
      }

#pragma unroll 1
      for (int iter = 0; iter < 2; ++iter) {
        const int rowbase = rc * 64 + iter * 32;
        short8v qhf[2][4], qlf[2][4];
#pragma unroll
        for (int s = 0; s < 2; ++s)
#pragma unroll
          for (int c = 0; c < 4; ++c) {
            size_t off = (size_t)(b * 512 + rowbase + s * 16 + lrow) * DIM + c * 32 + kgrp * 8;
            qhf[s][c] = *(const short8v*)(qh_g + off);
            qlf[s][c] = *(const short8v*)(ql_g + off);
          }

        f32x4 acc[2][2] = {{zero4, zero4}, {zero4, zero4}};
#pragma unroll
        for (int c = 0; c < 4; ++c)
#pragma unroll
          for (int slot = 0; slot < 2; ++slot) {
            int p = slot ? p1 : p0;
            if (p < 0) continue;
#pragma unroll
            for (int s = 0; s < 2; ++s) {
              if (p == 2) {   // V: swapped -> C[v][g]
                acc[slot][s] = MFMA(whf[slot][c], qlf[s][c], acc[slot][s]);
                acc[slot][s] = MFMA(wlf[slot][c], qhf[s][c], acc[slot][s]);
                acc[slot][s] = MFMA(whf[slot][c], qhf[s][c], acc[slot][s]);
              } else {
                acc[slot][s] = MFMA(qlf[s][c], whf[slot][c], acc[slot][s]);
                acc[slot][s] = MFMA(qhf[s][c], wlf[slot][c], acc[slot][s]);
                acc[slot][s] = MFMA(qhf[s][c], whf[slot][c], acc[slot][s]);
              }
            }
          }

#pragma unroll
        for (int slot = 0; slot < 2; ++slot) {
          int p = slot ? p1 : p0;
          if (p < 0) continue;
#pragma unroll
          for (int s = 0; s < 2; ++s) {
#pragma unroll
            for (int rg = 0; rg < 4; ++rg) {
              float x = acc[slot][s][rg];
              if (p == 2) {
                int v = kgrp * 4 + rg;
                int g = rowbase + s * 16 + lrow;
                Vt[hb * 8192 + (size_t)v * 512 + g] = f2bf(x);
              } else {
                int row = rowbase + s * 16 + kgrp * 4 + rg;
                if (p == 0) {
                  float xs = x * QSCALE;
                  ushort_t hi = f2bf(xs), lo = f2bf(xs - bf2f(hi));
                  size_t off = hb * 8192 + (size_t)row * 16 + lrow;
                  QcH[off] = hi; QcL[off] = lo;
                } else if (p == 1) {
                  ushort_t hi = f2bf(x), lo = f2bf(x - bf2f(hi));
                  size_t off = hb * 16384 + (size_t)row * 32 + lrow;
                  Kb[off] = hi; Kb[off + 16] = lo;
                } else {
                  bool lowr = (p == 3 || p == 4);
                  bool write = lowr ? (row <= NPK) : (row > NPK);
                  if (write) {
                    float xs = (row == 0) ? 0.f : x * QSCALE;
                    ushort_t hi = f2bf(xs), lo = f2bf(xs - bf2f(hi));
                    ushort_t* dH = (p == 3 || p == 5) ? QPH : QDH;
                    ushort_t* dL = (p == 3 || p == 5) ? QPL : QDL;
                    size_t off = hb * 8192 + (size_t)row * 16 + lrow;
                    dH[off] = hi; dL[off] = lo;
                  }
                }
              }
            }
          }
        }
      }
    }
  }
  grid.sync();

  // ============================ Phase 2: attn ============================
  {
    const int lhalf = lane >> 4, lcol = lane & 15;
    const int srcA = ((lhalf & 1) * 2) * 16 + lcol;
    const int srcB = srcA + 16;
    const bool selhi = (lhalf >= 2);
    const f32x4 zero4 = {0.f, 0.f, 0.f, 0.f};

#pragma unroll 1
    for (int tt = 0; tt < 2; ++tt) {
      const int tile = blockIdx.x * 2 + tt;          // 0..511
      const int rt = tile & 3, b = (tile >> 2) & 15, h = tile >> 6;
      const size_t hb = (size_t)h * NB + b;

      const ushort_t* Kg = Kb + hb * (size_t)(QROWS * 32);
      for (int c = tid; c < 2048; c += 512)
        *(short8v*)&Klds[c * 8] = *(const short8v*)(Kg + (size_t)c * 8);

      const ushort_t* Vg = Vt + hb * (size_t)(16 * QROWS);
#pragma unroll
      for (int it = 0; it < 2; ++it) {
        int i = it * 512 + tid;                      // 0..1023
        int v = (i >> 4) & 15;
        int blk = (i >> 8) * 16 + (i & 15);          // 0..63
        int g2 = blk >> 2, lh = blk & 3;
        short8v val = *(const short8v*)(Vg + (size_t)v * QROWS + blk * 8);
        *(short8v*)&Vlds[((g2 * 4 + lh) * 16 + v) * 8] = val;
      }
      __syncthreads();

      const int wrow = rt * 128 + wid * 16;          // wave owns 16 q-rows
      const int row = wrow + lcol;
      size_t off = hb * (size_t)(QROWS * 16) + (size_t)row * 16;
      size_t offh = off + (lhalf & 1) * 8;
      short8v qch = *(const short8v*)(QcH + offh);
      short8v qph = *(const short8v*)(QPH + offh);
      short8v qdh = *(const short8v*)(QDH + offh);
      short8v qcl = {0,0,0,0,0,0,0,0}, qpl = qcl, qdl = qcl;
      if (lhalf < 2) {
        size_t offl = off + lhalf * 8;
        qcl = *(const short8v*)(QcL + offl);
        qpl = *(const short8v*)(QPL + offl);
        qdl = *(const short8v*)(QDL + offl);
      }

      f32x4 Oacc = zero4;
      float lsum = 0.f;

#pragma unroll 1
      for (int grp = 0; grp < 16; ++grp) {
        float pv[2][4];
#pragma unroll
        for (int half = 0; half < 2; ++half) {
          const int ch = grp * 2 + half;
          short8v ka = *(const short8v*)&Klds[((ch * 16 + lcol) * 4 + lhalf) * 8];
          f32x4 sc = MFMA(ka, qcl, zero4);
          sc = MFMA(ka, qch, sc);
          f32x4 se;
          if (ch == 15) {
            f32x4 sp = MFMA(ka, qpl, zero4); sp = MFMA(ka, qph, sp);
            f32x4 sd = MFMA(ka, qdl, zero4); sd = MFMA(ka, qdh, sd);
#pragma unroll
            for (int rg = 0; rg < 4; ++rg) {
              int key = 240 + lhalf * 4 + rg;
              se[rg] = (key <= NPK) ? sp[rg] : sd[rg];
            }
          } else if (ch <= 14) {
            se = MFMA(ka, qpl, zero4); se = MFMA(ka, qph, se);
          } else {
            se = MFMA(ka, qdl, zero4); se = MFMA(ka, qdh, se);
          }
#pragma unroll
          for (int rg = 0; rg < 4; ++rg) {
            float ec = __builtin_amdgcn_exp2f(sc[rg]);
            float ee = (se[rg] == 0.0f) ? 0.0f : __builtin_amdgcn_exp2f(se[rg]);
            if (ch == 0 && rg == 0) ee = (lhalf == 0) ? 0.0f : ee;
            float pt = ec + ee;
            if (ch == 31) pt = (lhalf * 4 + rg <= 4) ? pt : 0.0f;
            lsum += pt;
            pv[half][rg] = pt;
          }
        }
        unsigned a0 = cvtpk(pv[0][0], pv[0][1]);
        unsigned a1 = cvtpk(pv[0][2], pv[0][3]);
        unsigned b0 = cvtpk(pv[1][0], pv[1][1]);
        unsigned b1 = cvtpk(pv[1][2], pv[1][3]);
        unsigned h0A = (unsigned)__shfl((int)a0, srcA);
        unsigned h0B = (unsigned)__shfl((int)a1, srcA);
        unsigned h0C = (unsigned)__shfl((int)a0, srcB);
        unsigned h0D = (unsigned)__shfl((int)a1, srcB);
        unsigned h1A = (unsigned)__shfl((int)b0, srcA);
        unsigned h1B = (unsigned)__shfl((int)b1, srcA);
        unsigned h1C = (unsigned)__shfl((int)b0, srcB);
        unsigned h1D = (unsigned)__shfl((int)b1, srcB);
        union { unsigned u[4]; short8v s; } pb;
        pb.u[0] = selhi ? h1A : h0A;
        pb.u[1] = selhi ? h1B : h0B;
        pb.u[2] = selhi ? h1C : h0C;
        pb.u[3] = selhi ? h1D : h0D;
        short8v va = *(const short8v*)&Vlds[((grp * 4 + lhalf) * 16 + lcol) * 8];
        Oacc = MFMA(va, pb.s, Oacc);
      }

      float l = lsum;
      l += __shfl_xor(l, 16);
      l += __shfl_xor(l, 32);
      float inv = 1.0f / l;
      if (row < NG) {
        short4v ph, pl;
#pragma unroll
        for (int rg = 0; rg < 4; ++rg) {
          float o = Oacc[rg] * inv;
          ushort_t hi = f2bf(o);
          ph[rg] = (short)hi;
          pl[rg] = (short)f2bf(o - bf2f(hi));
        }
        size_t doff = (hb * 512 + (size_t)row) * 16 + lhalf * 4;
        *(short4v*)&HdH[doff] = ph;
        *(short4v*)&HdL[doff] = pl;
      }
      __syncthreads();   // protect LDS before next tile restage
    }
  }
  grid.sync();

  // ============================ Phase 3: out =============================
  {
    const int rt = blockIdx.x & 15, b = blockIdx.x >> 4;
    const int lrow = lane & 15, kgrp = lane >> 4;
    const int e0 = wid * 16 + lrow;                  // 8 waves cover e 0..127

    short8v bh[4], bl[4];
#pragma unroll
    for (int c = 0; c < 4; ++c) {
      size_t off = (((size_t)c * 4 + kgrp) * 128 + e0) * 8;
      bh[c] = *(const short8v*)&Wosh[off];
      bl[c] = *(const short8v*)&Wosl[off];
    }

    short8v ah[2][4], al[2][4];
#pragma unroll
    for (int s = 0; s < 2; ++s)
#pragma unroll
      for (int c = 0; c < 4; ++c) {
        int hh = (c * 4 + kgrp) >> 1, kd0 = ((c * 4 + kgrp) & 1) * 8;
        size_t off = ((size_t)(hh * NB + b) * 512 + rt * 32 + s * 16 + lrow) * 16 + kd0;
        ah[s][c] = *(const short8v*)(HdH + off);
        al[s][c] = *(const short8v*)(HdL + off);
      }

    const f32x4 zero4 = {0.f, 0.f, 0.f, 0.f};
    f32x4 acc[2] = {zero4, zero4};
#pragma unroll
    for (int c = 0; c < 4; ++c)
#pragma unroll
      for (int s = 0; s < 2; ++s) {
        acc[s] = MFMA(al[s][c], bh[c], acc[s]);
        acc[s] = MFMA(ah[s][c], bl[c], acc[s]);
        acc[s] = MFMA(ah[s][c], bh[c], acc[s]);
      }

#pragma unroll
    for (int s = 0; s < 2; ++s)
#pragma unroll
      for (int rg = 0; rg < 4; ++rg) {
        int g = rt * 32 + s * 16 + kgrp * 4 + rg;
        if (g < NG) a.out[((size_t)b * NG + g) * 128 + e0] = acc[s][rg];
      }
  }
}

// ===========================================================================
// Fallback path: the proven R5 4-kernel pipeline (verbatim).
// ===========================================================================
__global__ __launch_bounds__(256) void conv_kernel(
    const float* __restrict__ q, ushort_t* __restrict__ qh,
    ushort_t* __restrict__ ql)
{
  int idx = blockIdx.x * 256 + threadIdx.x;
  int b  = idx >> 13;
  int r  = (idx >> 4) & 511;
  int c8 = (idx & 15) * 8;
  short8v h8 = {0,0,0,0,0,0,0,0}, l8 = {0,0,0,0,0,0,0,0};
  if (r < NG) {
    const float* src = &q[(size_t)(b * NG + r) * DIM + c8];
    float4 a = *(const float4*)src, d = *(const float4*)(src + 4);
    float vals[8] = {a.x, a.y, a.z, a.w, d.x, d.y, d.z, d.w};
#pragma unroll
    for (int j = 0; j < 8; ++j) {
      ushort_t hi = f2bf(vals[j]);
      h8[j] = (short)hi;
      l8[j] = (short)f2bf(vals[j] - bf2f(hi));
    }
  }
  size_t off = (size_t)(b * 512 + r) * DIM + c8;
  *(short8v*)&qh[off] = h8;
  *(short8v*)&ql[off] = l8;
}

__global__ __launch_bounds__(256) void proj_kernel(
    const ushort_t* __restrict__ qh_g, const ushort_t* __restrict__ ql_g,
    const float* __restrict__ wq, const float* __restrict__ wk,
    const float* __restrict__ wv, const float* __restrict__ w1,
    const float* __restrict__ w2, const float* __restrict__ w3,
    const float* __restrict__ w4,
    ushort_t* __restrict__ QcH, ushort_t* __restrict__ QcL,
    ushort_t* __restrict__ QPH, ushort_t* __restrict__ QPL,
    ushort_t* __restrict__ QDH, ushort_t* __restrict__ QDL,
    ushort_t* __restrict__ Kb,  ushort_t* __restrict__ Vt)
{
  const int rc = blockIdx.x, b = blockIdx.y, h = blockIdx.z;
  const int tid = threadIdx.x;
  const int wid = tid >> 6, lane = tid & 63;
  const int lrow = lane & 15, kgrp = lane >> 4;
  const size_t hb = (size_t)h * NB + b;

  const float* Wptr[7] = {wq, wk, wv, w1, w2, w3, w4};
  const int p0 = wid * 2;
  const int p1 = (wid < 3) ? wid * 2 + 1 : -1;

  short8v whf[2][4], wlf[2][4];
#pragma unroll
  for (int slot = 0; slot < 2; ++slot) {
    int p = slot ? p1 : p0;
    if (p < 0) continue;
    const float* W = Wptr[p] + h * 2048 + lrow;
#pragma unroll
    for (int c = 0; c < 4; ++c) {
      short8v hh, ll;
#pragma unroll
      for (int j = 0; j < 8; ++j) {
        float v = W[(c * 32 + kgrp * 8 + j) * 16];
        ushort_t hi = f2bf(v);
        hh[j] = (short)hi;
        ll[j] = (short)f2bf(v - bf2f(hi));
      }
      whf[slot][c] = hh; wlf[slot][c] = ll;
    }
  }

  const f32x4 zero4 = {0.f, 0.f, 0.f, 0.f};

#pragma unroll 1
  for (int iter = 0; iter < 2; ++iter) {
    const int rowbase = rc * 64 + iter * 32;
    short8v qhf[2][4], qlf[2][4];
#pragma unroll
    for (int s = 0; s < 2; ++s)
#pragma unroll
      for (int c = 0; c < 4; ++c) {
        size_t off = (size_t)(b * 512 + rowbase + s * 16 + lrow) * DIM + c * 32 + kgrp * 8;
        qhf[s][c] = *(const short8v*)(qh_g + off);
        qlf[s][c] = *(const short8v*)(ql_g + off);
      }

    f32x4 acc[2][2] = {{zero4, zero4}, {zero4, zero4}};
#pragma unroll
    for (int c = 0; c < 4; ++c)
#pragma unroll
      for (int slot = 0; slot < 2; ++slot) {
        int p = slot ? p1 : p0;
        if (p < 0) continue;
#pragma unroll
        for (int s = 0; s < 2; ++s) {
          if (p == 2) {
            acc[slot][s] = MFMA(whf[slot][c], qlf[s][c], acc[slot][s]);
            acc[slot][s] = MFMA(wlf[slot][c], qhf[s][c], acc[slot][s]);
            acc[slot][s] = MFMA(whf[slot][c], qhf[s][c], acc[slot][s]);
          } else {
            acc[slot][s] = MFMA(qlf[s][c], whf[slot][c], acc[slot][s]);
            acc[slot][s] = MFMA(qhf[s][c], wlf[slot][c], acc[slot][s]);
            acc[slot][s] = MFMA(qhf[s][c], whf[slot][c], acc[slot][s]);
          }
        }
      }

#pragma unroll
    for (int slot = 0; slot < 2; ++slot) {
      int p = slot ? p1 : p0;
      if (p < 0) continue;
#pragma unroll
      for (int s = 0; s < 2; ++s) {
#pragma unroll
        for (int rg = 0; rg < 4; ++rg) {
          float x = acc[slot][s][rg];
          if (p == 2) {
            int v = kgrp * 4 + rg;
            int g = rowbase + s * 16 + lrow;
            Vt[hb * 8192 + (size_t)v * 512 + g] = f2bf(x);
          } else {
            int row = rowbase + s * 16 + kgrp * 4 + rg;
            if (p == 0) {
              float xs = x * QSCALE;
              ushort_t hi = f2bf(xs), lo = f2bf(xs - bf2f(hi));
              size_t off = hb * 8192 + (size_t)row * 16 + lrow;
              QcH[off] = hi; QcL[off] = lo;
            } else if (p == 1) {
              ushort_t hi = f2bf(x), lo = f2bf(x - bf2f(hi));
              size_t off = hb * 16384 + (size_t)row * 32 + lrow;
              Kb[off] = hi; Kb[off + 16] = lo;
            } else {
              bool lowr = (p == 3 || p == 4);
              bool write = lowr ? (row <= NPK) : (row > NPK);
              if (write) {
                float xs = (row == 0) ? 0.f : x * QSCALE;
                ushort_t hi = f2bf(xs), lo = f2bf(xs - bf2f(hi));
                ushort_t* dH = (p == 3 || p == 5) ? QPH : QDH;
                ushort_t* dL = (p == 3 || p == 5) ? QPL : QDL;
                size_t off = hb * 8192 + (size_t)row * 16 + lrow;
                dH[off] = hi; dL[off] = lo;
              }
            }
          }
        }
      }
    }
  }
}

__global__ __launch_bounds__(256, 2) void attn_kernel(
    const ushort_t* __restrict__ QcH, const ushort_t* __restrict__ QcL,
    const ushort_t* __restrict__ QPH, const ushort_t* __restrict__ QPL,
    const ushort_t* __restrict__ QDH, const ushort_t* __restrict__ QDL,
    const ushort_t* __restrict__ Kb,  const ushort_t* __restrict__ Vt,
    ushort_t* __restrict__ HdH, ushort_t* __restrict__ HdL)
{
  __shared__ __align__(16) ushort_t Klds[16384];
  __shared__ __align__(16) ushort_t Vlds[8192];

  const int rt = blockIdx.x, b = blockIdx.y, h = blockIdx.z;
  const int tid = threadIdx.x;
  const int wid = tid >> 6, lane = tid & 63;
  const int lhalf = lane >> 4, lcol = lane & 15;
  const size_t hb = (size_t)h * NB + b;

  const ushort_t* Kg = Kb + hb * (size_t)(QROWS * 32);
  for (int c = tid; c < 2048; c += 256)
    *(short8v*)&Klds[c * 8] = *(const short8v*)(Kg + (size_t)c * 8);

  const ushort_t* Vg = Vt + hb * (size_t)(16 * QROWS);
#pragma unroll
  for (int it = 0; it < 4; ++it) {
    int c = it * 256 + tid;
    int blk = (it * 16) + (c & 15);
    int v = (c >> 4) & 15;
    int g2 = blk >> 2, lh = blk & 3;
    short8v val = *(const short8v*)(Vg + (size_t)v * QROWS + blk * 8);
    *(short8v*)&Vlds[((g2 * 4 + lh) * 16 + v) * 8] = val;
  }
  __syncthreads();

  const int wrow = rt * 128 + wid * 32;
  short8v qch[2], qcl[2], qph[2], qpl[2], qdh[2], qdl[2];
#pragma unroll
  for (int f = 0; f < 2; ++f) {
    int row = wrow + f * 16 + lcol;
    size_t off = hb * (size_t)(QROWS * 16) + (size_t)row * 16;
    size_t offh = off + (lhalf & 1) * 8;
    qch[f] = *(const short8v*)(QcH + offh);
    qph[f] = *(const short8v*)(QPH + offh);
    qdh[f] = *(const short8v*)(QDH + offh);
    short8v zl = {0,0,0,0,0,0,0,0};
    qcl[f] = zl; qpl[f] = zl; qdl[f] = zl;
    if (lhalf < 2) {
      size_t offl = off + lhalf * 8;
      qcl[f] = *(const short8v*)(QcL + offl);
      qpl[f] = *(const short8v*)(QPL + offl);
      qdl[f] = *(const short8v*)(QDL + offl);
    }
  }

  const f32x4 zero4 = {0.f, 0.f, 0.f, 0.f};
  f32x4 Oacc[2] = {zero4, zero4};
  float lsum[2] = {0.f, 0.f};
  const int srcA = ((lhalf & 1) * 2) * 16 + lcol;
  const int srcB = srcA + 16;
  const bool selhi = (lhalf >= 2);

#pragma unroll 1
  for (int grp = 0; grp < 16; ++grp) {
    float pv[2][2][4];
#pragma unroll
    for (int half = 0; half < 2; ++half) {
      const int ch = grp * 2 + half;
      short8v ka = *(const short8v*)&Klds[((ch * 16 + lcol) * 4 + lhalf) * 8];
#pragma unroll
      for (int qf = 0; qf < 2; ++qf) {
        f32x4 sc = MFMA(ka, qcl[qf], zero4);
        sc = MFMA(ka, qch[qf], sc);
        f32x4 se;
        if (ch == 15) {
          f32x4 sp = MFMA(ka, qpl[qf], zero4); sp = MFMA(ka, qph[qf], sp);
          f32x4 sd = MFMA(ka, qdl[qf], zero4); sd = MFMA(ka, qdh[qf], sd);
#pragma unroll
          for (int rg = 0; rg < 4; ++rg) {
            int key = 240 + lhalf * 4 + rg;
            se[rg] = (key <= NPK) ? sp[rg] : sd[rg];
          }
        } else if (ch <= 14) {
          se = MFMA(ka, qpl[qf], zero4); se = MFMA(ka, qph[qf], se);
        } else {
          se = MFMA(ka, qdl[qf], zero4); se = MFMA(ka, qdh[qf], se);
        }
#pragma unroll
        for (int rg = 0; rg < 4; ++rg) {
          float ec = __builtin_amdgcn_exp2f(sc[rg]);
          float ee = (se[rg] == 0.0f) ? 0.0f : __builtin_amdgcn_exp2f(se[rg]);
          if (ch == 0 && rg == 0) ee = (lhalf == 0) ? 0.0f : ee;
          float pt = ec + ee;
          if (ch == 31) pt = (lhalf * 4 + rg <= 4) ? pt : 0.0f;
          lsum[qf] += pt;
          pv[half][qf][rg] = pt;
        }
      }
    }
#pragma unroll
    for (int qf = 0; qf < 2; ++qf) {
      unsigned a0 = cvtpk(pv[0][qf][0], pv[0][qf][1]);
      unsigned a1 = cvtpk(pv[0][qf][2], pv[0][qf][3]);
      unsigned b0 = cvtpk(pv[1][qf][0], pv[1][qf][1]);
      unsigned b1 = cvtpk(pv[1][qf][2], pv[1][qf][3]);
      unsigned h0A = (unsigned)__shfl((int)a0, srcA);
      unsigned h0B = (unsigned)__shfl((int)a1, srcA);
      unsigned h0C = (unsigned)__shfl((int)a0, srcB);
      unsigned h0D = (unsigned)__shfl((int)a1, srcB);
      unsigned h1A = (unsigned)__shfl((int)b0, srcA);
      unsigned h1B = (unsigned)__shfl((int)b1, srcA);
      unsigned h1C = (unsigned)__shfl((int)b0, srcB);
      unsigned h1D = (unsigned)__shfl((int)b1, srcB);
      union { unsigned u[4]; short8v s; } pb;
      pb.u[0] = selhi ? h1A : h0A;
      pb.u[1] = selhi ? h1B : h0B;
      pb.u[2] = selhi ? h1C : h0C;
      pb.u[3] = selhi ? h1D : h0D;
      short8v va = *(const short8v*)&Vlds[((grp * 4 + lhalf) * 16 + lcol) * 8];
      Oacc[qf] = MFMA(va, pb.s, Oacc[qf]);
    }
  }

#pragma unroll
  for (int qf = 0; qf < 2; ++qf) {
    float l = lsum[qf];
    l += __shfl_xor(l, 16);
    l += __shfl_xor(l, 32);
    float inv = 1.0f / l;
    int row = wrow + qf * 16 + lcol;
    if (row < NG) {
      short4v ph, pl;
#pragma unroll
      for (int rg = 0; rg < 4; ++rg) {
        float o = Oacc[qf][rg] * inv;
        ushort_t hi = f2bf(o);
        ph[rg] = (short)hi;
        pl[rg] = (short)f2bf(o - bf2f(hi));
      }
      size_t off = (hb * 512 + (size_t)row) * 16 + lhalf * 4;
      *(short4v*)&HdH[off] = ph;
      *(short4v*)&HdL[off] = pl;
    }
  }
}

__global__ __launch_bounds__(256) void out_kernel(
    const ushort_t* __restrict__ HdH, const ushort_t* __restrict__ HdL,
    const float* __restrict__ Wout, float* __restrict__ out)
{
  const int eh = blockIdx.x, rt = blockIdx.y, b = blockIdx.z;
  const int tid = threadIdx.x;
  const int wid = tid >> 6, lane = tid & 63;
  const int lrow = lane & 15, kgrp = lane >> 4;
  const int e0 = eh * 64 + wid * 16 + lrow;

  short8v bh[4], bl[4];
#pragma unroll
  for (int c = 0; c < 4; ++c) {
    short8v hh, ll;
#pragma unroll
    for (int j = 0; j < 8; ++j) {
      float v = Wout[(size_t)(c * 32 + kgrp * 8 + j) * 128 + e0];
      ushort_t hi = f2bf(v);
      hh[j] = (short)hi;
      ll[j] = (short)f2bf(v - bf2f(hi));
    }
    bh[c] = hh; bl[c] = ll;
  }

  short8v ah[2][4], al[2][4];
#pragma unroll
  for (int s = 0; s < 2; ++s)
#pragma unroll
    for (int c = 0; c < 4; ++c) {
      int hh = (c * 4 + kgrp) >> 1, kd0 = ((c * 4 + kgrp) & 1) * 8;
      size_t off = ((size_t)(hh * NB + b) * 512 + rt * 32 + s * 16 + lrow) * 16 + kd0;
      ah[s][c] = *(const short8v*)(HdH + off);
      al[s][c] = *(const short8v*)(HdL + off);
    }

  const f32x4 zero4 = {0.f, 0.f, 0.f, 0.f};
  f32x4 acc[2] = {zero4, zero4};
#pragma unroll
  for (int c = 0; c < 4; ++c)
#pragma unroll
    for (int s = 0; s < 2; ++s) {
      acc[s] = MFMA(al[s][c], bh[c], acc[s]);
      acc[s] = MFMA(ah[s][c], bl[c], acc[s]);
      acc[s] = MFMA(ah[s][c], bh[c], acc[s]);
    }

#pragma unroll
  for (int s = 0; s < 2; ++s)
#pragma unroll
    for (int rg = 0; rg < 4; ++rg) {
      int g = rt * 32 + s * 16 + kgrp * 4 + rg;
      if (g < NG) out[((size_t)b * NG + g) * 128 + e0] = acc[s][rg];
    }
}

// ===========================================================================
extern "C" void kernel_launch(void* const* d_in, const int* in_sizes, int n_in,
                              void* d_out, int out_size, void* d_ws, size_t ws_size,
                              hipStream_t stream)
{
  FArgs a;
  a.q  = (const float*)d_in[0];
  a.wq = (const float*)d_in[1];
  a.wk = (const float*)d_in[2];
  a.wv = (const float*)d_in[3];
  a.w1 = (const float*)d_in[4];
  a.w2 = (const float*)d_in[5];
  a.w3 = (const float*)d_in[6];
  a.w4 = (const float*)d_in[7];
  a.wo = (const float*)d_in[8];
  a.out = (float*)d_out;
  a.ws  = (char*)d_ws;

  bool done = false;
  int nb = 0;
  hipError_t qe = hipOccupancyMaxActiveBlocksPerMultiprocessor(&nb, fused_kernel, 512, 0);
  if (qe == hipSuccess && nb >= 1) {
    void* kp[] = {&a};
    hipError_t le = hipLaunchCooperativeKernel(fused_kernel, dim3(256), dim3(512), kp, 0, stream);
    done = (le == hipSuccess);
  }

  if (!done) {
    char* wsb = (char*)d_ws;
    ushort_t* qh_g = (ushort_t*)(wsb + (0u  << 20));
    ushort_t* ql_g = (ushort_t*)(wsb + (2u  << 20));
    ushort_t* QcH  = (ushort_t*)(wsb + (4u  << 20));
    ushort_t* QcL  = (ushort_t*)(wsb + (6u  << 20));
    ushort_t* QPH  = (ushort_t*)(wsb + (8u  << 20));
    ushort_t* QPL  = (ushort_t*)(wsb + (10u << 20));
    ushort_t* QDH  = (ushort_t*)(wsb + (12u << 20));
    ushort_t* QDL  = (ushort_t*)(wsb + (14u << 20));
    ushort_t* Kb   = (ushort_t*)(wsb + (16u << 20));
    ushort_t* Vt   = (ushort_t*)(wsb + (20u << 20));
    ushort_t* HdH  = qh_g;
    ushort_t* HdL  = ql_g;

    conv_kernel<<<dim3(512), 256, 0, stream>>>(a.q, qh_g, ql_g);
    proj_kernel<<<dim3(8, NB, NH), 256, 0, stream>>>(qh_g, ql_g,
                                                     a.wq, a.wk, a.wv, a.w1, a.w2, a.w3, a.w4,
                                                     QcH, QcL, QPH, QPL, QDH, QDL, Kb, Vt);
    attn_kernel<<<dim3(4, NB, NH), 256, 0, stream>>>(QcH, QcL, QPH, QPL, QDH, QDL,
                                                     Kb, Vt, HdH, HdL);
    out_kernel<<<dim3(2, 16, NB), 256, 0, stream>>>(HdH, HdL, a.wo, out_size ? (float*)d_out : nullptr);
  }
}

// Round 10
// 124.563 us; speedup vs baseline: 1.0454x; 1.0454x over previous
//
#include <hip/hip_runtime.h>
#include <math.h>

// Problem constants (match reference setup_inputs)
#define NH 8
#define DIM 128
#define KD 16
#define NB 16
#define NG 501
#define NPK 250
#define QROWS 512
// nf * log2(e) = 0.25 * 1.4426950408889634
#define QSCALE 0.36067376022224085f

typedef unsigned short ushort_t;
typedef __attribute__((ext_vector_type(8))) short short8v;
typedef __attribute__((ext_vector_type(4))) short short4v;
typedef __attribute__((ext_vector_type(4))) float f32x4;

#define MFMA(a, b, c) __builtin_amdgcn_mfma_f32_16x16x32_bf16(a, b, c, 0, 0, 0)

static __device__ __forceinline__ ushort_t f2bf(float x) {  // RNE, finite only
  union { float f; unsigned u; } v; v.f = x;
  unsigned r = v.u + 0x7FFFu + ((v.u >> 16) & 1u);
  return (ushort_t)(r >> 16);
}
static __device__ __forceinline__ float bf2f(ushort_t h) {
  union { unsigned u; float f; } v; v.u = ((unsigned)h) << 16;
  return v.f;
}
static __device__ __forceinline__ unsigned cvtpk(float lo, float hi) {
  unsigned r;
  asm("v_cvt_pk_bf16_f32 %0, %1, %2" : "=v"(r) : "v"(lo), "v"(hi));
  return r;
}

// ws layout (1 MB units)
//  0: qh_g [16][512][128] (2MB) -- aliased as HdH after proj
//  2: ql_g (2MB)                -- aliased as HdL
//  4: QcH [128hb][512][16]  6: QcL   8: QPH  10: QPL  12: QDH  14: QDL
// 16: Kb  [128hb][512][32] (4MB)
// 20: Vt  [128hb][16][512] (2MB)
// 22: Wsh frag-layout (224KB)  23: Wsl
// 24: Wosh (256KB)             25: Wosl

// ---------------------------------------------------------------------------
// Kernel 0: q split + W / Wout pre-split into MFMA frag layout (hi/lo bf16).
// ---------------------------------------------------------------------------
__global__ __launch_bounds__(256) void conv_kernel(
    const float* __restrict__ q,
    const float* __restrict__ wq, const float* __restrict__ wk,
    const float* __restrict__ wv, const float* __restrict__ w1,
    const float* __restrict__ w2, const float* __restrict__ w3,
    const float* __restrict__ w4, const float* __restrict__ wo,
    ushort_t* __restrict__ qh_g, ushort_t* __restrict__ ql_g,
    ushort_t* __restrict__ Wsh,  ushort_t* __restrict__ Wsl,
    ushort_t* __restrict__ Wosh, ushort_t* __restrict__ Wosl)
{
  const int idx = blockIdx.x * 256 + threadIdx.x;   // 0..131071
  {
    int b = idx >> 13, r = (idx >> 4) & 511, c8 = (idx & 15) * 8;
    short8v h8 = {0,0,0,0,0,0,0,0}, l8 = {0,0,0,0,0,0,0,0};
    if (r < NG) {
      const float* src = &q[(size_t)(b * NG + r) * DIM + c8];
      float4 x = *(const float4*)src, y = *(const float4*)(src + 4);
      float vals[8] = {x.x, x.y, x.z, x.w, y.x, y.y, y.z, y.w};
#pragma unroll
      for (int j = 0; j < 8; ++j) {
        ushort_t hi = f2bf(vals[j]);
        h8[j] = (short)hi;
        l8[j] = (short)f2bf(vals[j] - bf2f(hi));
      }
    }
    size_t off = (size_t)(b * 512 + r) * DIM + c8;
    *(short8v*)&qh_g[off] = h8;
    *(short8v*)&ql_g[off] = l8;
  }
  if (idx < 114688) {   // 7 projection W's -> frag layout hi/lo
    int p = idx >> 14, rem = idx & 16383;
    int h = rem >> 11, r2 = rem & 2047;
    int d = r2 >> 4, lrow = r2 & 15;
    const float* W = (p == 0) ? wq : (p == 1) ? wk : (p == 2) ? wv :
                     (p == 3) ? w1 : (p == 4) ? w2 : (p == 5) ? w3 : w4;
    float v = W[h * 2048 + d * 16 + lrow];
    ushort_t hi = f2bf(v), lo = f2bf(v - bf2f(hi));
    int c = d >> 5, kg = (d >> 3) & 3, j = d & 7;
    size_t dst = ((((size_t)(p * 8 + h) * 4 + c) * 4 + kg) * 16 + lrow) * 8 + j;
    Wsh[dst] = hi; Wsl[dst] = lo;
  }
  if (idx < 16384) {    // Wout -> frag layout hi/lo
    int hkd = idx >> 7, e = idx & 127;
    float v = wo[(size_t)hkd * 128 + e];
    ushort_t hi = f2bf(v), lo = f2bf(v - bf2f(hi));
    int c = hkd >> 5, kg = (hkd >> 3) & 3, j = hkd & 7;
    size_t dst = (((size_t)c * 4 + kg) * 128 + e) * 8 + j;
    Wosh[dst] = hi; Wosl[dst] = lo;
  }
}

// ---------------------------------------------------------------------------
// Kernel 1: MFMA projections; 1024 blocks x 256 thr = 16 waves/CU.
// Per-c loads keep VGPR < 128 (no spill under launch_bounds cap).
// ---------------------------------------------------------------------------
__global__ __launch_bounds__(256, 4) void proj_kernel(
    const ushort_t* __restrict__ qh_g, const ushort_t* __restrict__ ql_g,
    const ushort_t* __restrict__ Wsh,  const ushort_t* __restrict__ Wsl,
    ushort_t* __restrict__ QcH, ushort_t* __restrict__ QcL,
    ushort_t* __restrict__ QPH, ushort_t* __restrict__ QPL,
    ushort_t* __restrict__ QDH, ushort_t* __restrict__ QDL,
    ushort_t* __restrict__ Kb,  ushort_t* __restrict__ Vt)
{
  const int rc = blockIdx.x, b = blockIdx.y, h = blockIdx.z;
  const int tid = threadIdx.x;
  const int wid = tid >> 6, lane = tid & 63;
  const int lrow = lane & 15, kgrp = lane >> 4;
  const size_t hb = (size_t)h * NB + b;
  const int p0 = wid * 2;
  const int p1 = (wid < 3) ? wid * 2 + 1 : -1;
  const f32x4 zero4 = {0.f, 0.f, 0.f, 0.f};

#pragma unroll 1
  for (int iter = 0; iter < 2; ++iter) {
    const int rowbase = rc * 64 + iter * 32;
    f32x4 acc[2][2] = {{zero4, zero4}, {zero4, zero4}};
#pragma unroll
    for (int c = 0; c < 4; ++c) {
      size_t qoff0 = (size_t)(b * 512 + rowbase + lrow) * DIM + c * 32 + kgrp * 8;
      size_t qoff1 = qoff0 + 16 * DIM;
      short8v qh0 = *(const short8v*)(qh_g + qoff0);
      short8v ql0 = *(const short8v*)(ql_g + qoff0);
      short8v qh1 = *(const short8v*)(qh_g + qoff1);
      short8v ql1 = *(const short8v*)(ql_g + qoff1);
#pragma unroll
      for (int slot = 0; slot < 2; ++slot) {
        int p = slot ? p1 : p0;
        if (p < 0) continue;
        size_t woff = ((((size_t)(p * 8 + h) * 4 + c) * 4 + kgrp) * 16 + lrow) * 8;
        short8v wh = *(const short8v*)&Wsh[woff];
        short8v wl = *(const short8v*)&Wsl[woff];
        if (p == 2) {   // V: swapped operands -> C[v][g]
          acc[slot][0] = MFMA(wh, ql0, acc[slot][0]);
          acc[slot][0] = MFMA(wl, qh0, acc[slot][0]);
          acc[slot][0] = MFMA(wh, qh0, acc[slot][0]);
          acc[slot][1] = MFMA(wh, ql1, acc[slot][1]);
          acc[slot][1] = MFMA(wl, qh1, acc[slot][1]);
          acc[slot][1] = MFMA(wh, qh1, acc[slot][1]);
        } else {
          acc[slot][0] = MFMA(ql0, wh, acc[slot][0]);
          acc[slot][0] = MFMA(qh0, wl, acc[slot][0]);
          acc[slot][0] = MFMA(qh0, wh, acc[slot][0]);
          acc[slot][1] = MFMA(ql1, wh, acc[slot][1]);
          acc[slot][1] = MFMA(qh1, wl, acc[slot][1]);
          acc[slot][1] = MFMA(qh1, wh, acc[slot][1]);
        }
      }
    }

    // stores (identical semantics to validated R5 path)
#pragma unroll
    for (int slot = 0; slot < 2; ++slot) {
      int p = slot ? p1 : p0;
      if (p < 0) continue;
#pragma unroll
      for (int s = 0; s < 2; ++s) {
#pragma unroll
        for (int rg = 0; rg < 4; ++rg) {
          float x = acc[slot][s][rg];
          if (p == 2) {
            int v = kgrp * 4 + rg;
            int g = rowbase + s * 16 + lrow;
            Vt[hb * 8192 + (size_t)v * 512 + g] = f2bf(x);
          } else {
            int row = rowbase + s * 16 + kgrp * 4 + rg;
            if (p == 0) {
              float xs = x * QSCALE;
              ushort_t hi = f2bf(xs), lo = f2bf(xs - bf2f(hi));
              size_t off = hb * 8192 + (size_t)row * 16 + lrow;
              QcH[off] = hi; QcL[off] = lo;
            } else if (p == 1) {
              ushort_t hi = f2bf(x), lo = f2bf(x - bf2f(hi));
              size_t off = hb * 16384 + (size_t)row * 32 + lrow;
              Kb[off] = hi; Kb[off + 16] = lo;
            } else {
              bool lowr = (p == 3 || p == 4);
              bool write = lowr ? (row <= NPK) : (row > NPK);
              if (write) {
                float xs = (row == 0) ? 0.f : x * QSCALE;
                ushort_t hi = f2bf(xs), lo = f2bf(xs - bf2f(hi));
                ushort_t* dH = (p == 3 || p == 5) ? QPH : QDH;
                ushort_t* dL = (p == 3 || p == 5) ? QPL : QDL;
                size_t off = hb * 8192 + (size_t)row * 16 + lrow;
                dH[off] = hi; dL[off] = lo;
              }
            }
          }
        }
      }
    }
  }
}

// ---------------------------------------------------------------------------
// Kernel 2: fused MFMA attention; 512 blocks x 512 thr = 16 waves/CU.
// Single q-frag per wave (16 q-rows); in-register P-transpose.
// ---------------------------------------------------------------------------
__global__ __launch_bounds__(512, 4) void attn_kernel(
    const ushort_t* __restrict__ QcH, const ushort_t* __restrict__ QcL,
    const ushort_t* __restrict__ QPH, const ushort_t* __restrict__ QPL,
    const ushort_t* __restrict__ QDH, const ushort_t* __restrict__ QDL,
    const ushort_t* __restrict__ Kb,  const ushort_t* __restrict__ Vt,
    ushort_t* __restrict__ HdH, ushort_t* __restrict__ HdL)
{
  __shared__ __align__(16) ushort_t Klds[16384];   // [key512][hi16|lo16]
  __shared__ __align__(16) ushort_t Vlds[8192];    // [grp16][lh4][v16][8]

  const int rt = blockIdx.x, b = blockIdx.y, h = blockIdx.z;
  const int tid = threadIdx.x;
  const int wid = tid >> 6, lane = tid & 63;
  const int lhalf = lane >> 4, lcol = lane & 15;
  const size_t hb = (size_t)h * NB + b;

  // Q loads issued first (overlap staging + barrier)
  const int wrow = rt * 128 + wid * 16;
  const int row = wrow + lcol;
  size_t off = hb * (size_t)(QROWS * 16) + (size_t)row * 16;
  size_t offh = off + (lhalf & 1) * 8;
  short8v qch = *(const short8v*)(QcH + offh);
  short8v qph = *(const short8v*)(QPH + offh);
  short8v qdh = *(const short8v*)(QDH + offh);
  short8v qcl = {0,0,0,0,0,0,0,0}, qpl = qcl, qdl = qcl;
  if (lhalf < 2) {
    size_t offl = off + lhalf * 8;
    qcl = *(const short8v*)(QcL + offl);
    qpl = *(const short8v*)(QPL + offl);
    qdl = *(const short8v*)(QDL + offl);
  }

  // stage K (linear 16B copy) and V (blocked)
  const ushort_t* Kg = Kb + hb * (size_t)(QROWS * 32);
  for (int c = tid; c < 2048; c += 512)
    *(short8v*)&Klds[c * 8] = *(const short8v*)(Kg + (size_t)c * 8);
  const ushort_t* Vg = Vt + hb * (size_t)(16 * QROWS);
#pragma unroll
  for (int it = 0; it < 2; ++it) {
    int i = it * 512 + tid;
    int v = (i >> 4) & 15;
    int blk = (i >> 8) * 16 + (i & 15);
    int g2 = blk >> 2, lh = blk & 3;
    short8v val = *(const short8v*)(Vg + (size_t)v * QROWS + blk * 8);
    *(short8v*)&Vlds[((g2 * 4 + lh) * 16 + v) * 8] = val;
  }
  __syncthreads();

  const f32x4 zero4 = {0.f, 0.f, 0.f, 0.f};
  f32x4 Oacc = zero4;
  float lsum = 0.f;
  const int srcA = ((lhalf & 1) * 2) * 16 + lcol;
  const int srcB = srcA + 16;
  const bool selhi = (lhalf >= 2);

#pragma unroll 1
  for (int grp = 0; grp < 16; ++grp) {
    const int ch0 = grp * 2, ch1 = ch0 + 1;
    // issue all LDS reads for this group up-front
    short8v ka0 = *(const short8v*)&Klds[((ch0 * 16 + lcol) * 4 + lhalf) * 8];
    short8v ka1 = *(const short8v*)&Klds[((ch1 * 16 + lcol) * 4 + lhalf) * 8];
    short8v va  = *(const short8v*)&Vlds[((grp * 4 + lhalf) * 16 + lcol) * 8];

    float pv[2][4];
#pragma unroll
    for (int half = 0; half < 2; ++half) {
      const int ch = ch0 + half;
      short8v ka = half ? ka1 : ka0;
      f32x4 sc = MFMA(ka, qcl, zero4);
      sc = MFMA(ka, qch, sc);
      f32x4 se;
      if (ch == 15) {                       // straddles pick/del at 250/251
        f32x4 sp = MFMA(ka, qpl, zero4); sp = MFMA(ka, qph, sp);
        f32x4 sd = MFMA(ka, qdl, zero4); sd = MFMA(ka, qdh, sd);
#pragma unroll
        for (int rg = 0; rg < 4; ++rg) {
          int key = 240 + lhalf * 4 + rg;
          se[rg] = (key <= NPK) ? sp[rg] : sd[rg];
        }
      } else if (ch <= 14) {                // pure pick-key range
        se = MFMA(ka, qpl, zero4); se = MFMA(ka, qph, se);
      } else {                              // pure delivery-key range
        se = MFMA(ka, qdl, zero4); se = MFMA(ka, qdh, se);
      }
#pragma unroll
      for (int rg = 0; rg < 4; ++rg) {
        float ec = __builtin_amdgcn_exp2f(sc[rg]);
        float ee = (se[rg] == 0.0f) ? 0.0f : __builtin_amdgcn_exp2f(se[rg]);
        if (ch == 0 && rg == 0) ee = (lhalf == 0) ? 0.0f : ee;   // key 0
        float pt = ec + ee;
        if (ch == 31) pt = (lhalf * 4 + rg <= 4) ? pt : 0.0f;    // keys > 500
        lsum += pt;
        pv[half][rg] = pt;
      }
    }
    // in-register transpose to P^T B-frag
    unsigned a0 = cvtpk(pv[0][0], pv[0][1]);
    unsigned a1 = cvtpk(pv[0][2], pv[0][3]);
    unsigned b0 = cvtpk(pv[1][0], pv[1][1]);
    unsigned b1 = cvtpk(pv[1][2], pv[1][3]);
    unsigned h0A = (unsigned)__shfl((int)a0, srcA);
    unsigned h0B = (unsigned)__shfl((int)a1, srcA);
    unsigned h0C = (unsigned)__shfl((int)a0, srcB);
    unsigned h0D = (unsigned)__shfl((int)a1, srcB);
    unsigned h1A = (unsigned)__shfl((int)b0, srcA);
    unsigned h1B = (unsigned)__shfl((int)b1, srcA);
    unsigned h1C = (unsigned)__shfl((int)b0, srcB);
    unsigned h1D = (unsigned)__shfl((int)b1, srcB);
    union { unsigned u[4]; short8v s; } pb;
    pb.u[0] = selhi ? h1A : h0A;
    pb.u[1] = selhi ? h1B : h0B;
    pb.u[2] = selhi ? h1C : h0C;
    pb.u[3] = selhi ? h1D : h0D;
    Oacc = MFMA(va, pb.s, Oacc);            // O^T[v=lh*4+rg][q=lcol]
  }

  float l = lsum;
  l += __shfl_xor(l, 16);
  l += __shfl_xor(l, 32);
  float inv = 1.0f / l;
  if (row < NG) {
    short4v ph, pl;
#pragma unroll
    for (int rg = 0; rg < 4; ++rg) {
      float o = Oacc[rg] * inv;
      ushort_t hi = f2bf(o);
      ph[rg] = (short)hi;
      pl[rg] = (short)f2bf(o - bf2f(hi));
    }
    size_t doff = (hb * 512 + (size_t)row) * 16 + lhalf * 4;
    *(short4v*)&HdH[doff] = ph;
    *(short4v*)&HdL[doff] = pl;
  }
}

// ---------------------------------------------------------------------------
// Kernel 3: MFMA output projection; 1024 blocks x 256 thr = 16 waves/CU.
// ---------------------------------------------------------------------------
__global__ __launch_bounds__(256, 4) void out_kernel(
    const ushort_t* __restrict__ HdH, const ushort_t* __restrict__ HdL,
    const ushort_t* __restrict__ Wosh, const ushort_t* __restrict__ Wosl,
    float* __restrict__ out)
{
  const int eh = blockIdx.x >> 1, s = blockIdx.x & 1;
  const int rt = blockIdx.y, b = blockIdx.z;
  const int tid = threadIdx.x;
  const int wid = tid >> 6, lane = tid & 63;
  const int lrow = lane & 15, kgrp = lane >> 4;
  const int e0 = eh * 64 + wid * 16 + lrow;

  short8v bh[4], bl[4], ah[4], al[4];
#pragma unroll
  for (int c = 0; c < 4; ++c) {
    size_t boff = (((size_t)c * 4 + kgrp) * 128 + e0) * 8;
    bh[c] = *(const short8v*)&Wosh[boff];
    bl[c] = *(const short8v*)&Wosl[boff];
    int hh = (c * 4 + kgrp) >> 1, kd0 = ((c * 4 + kgrp) & 1) * 8;
    size_t aoff = ((size_t)(hh * NB + b) * 512 + rt * 32 + s * 16 + lrow) * 16 + kd0;
    ah[c] = *(const short8v*)(HdH + aoff);
    al[c] = *(const short8v*)(HdL + aoff);
  }

  const f32x4 zero4 = {0.f, 0.f, 0.f, 0.f};
  f32x4 acc = zero4;
#pragma unroll
  for (int c = 0; c < 4; ++c) {
    acc = MFMA(al[c], bh[c], acc);
    acc = MFMA(ah[c], bl[c], acc);
    acc = MFMA(ah[c], bh[c], acc);
  }

#pragma unroll
  for (int rg = 0; rg < 4; ++rg) {
    int g = rt * 32 + s * 16 + kgrp * 4 + rg;
    if (g < NG) out[((size_t)b * NG + g) * 128 + e0] = acc[rg];
  }
}

// ===========================================================================
extern "C" void kernel_launch(void* const* d_in, const int* in_sizes, int n_in,
                              void* d_out, int out_size, void* d_ws, size_t ws_size,
                              hipStream_t stream)
{
  const float* q  = (const float*)d_in[0];
  const float* Wq = (const float*)d_in[1];
  const float* Wk = (const float*)d_in[2];
  const float* Wv = (const float*)d_in[3];
  const float* W1 = (const float*)d_in[4];
  const float* W2 = (const float*)d_in[5];
  const float* W3 = (const float*)d_in[6];
  const float* W4 = (const float*)d_in[7];
  const float* Wo = (const float*)d_in[8];
  float* out = (float*)d_out;

  char* wsb = (char*)d_ws;
  ushort_t* qh_g = (ushort_t*)(wsb + (0u  << 20));
  ushort_t* ql_g = (ushort_t*)(wsb + (2u  << 20));
  ushort_t* QcH  = (ushort_t*)(wsb + (4u  << 20));
  ushort_t* QcL  = (ushort_t*)(wsb + (6u  << 20));
  ushort_t* QPH  = (ushort_t*)(wsb + (8u  << 20));
  ushort_t* QPL  = (ushort_t*)(wsb + (10u << 20));
  ushort_t* QDH  = (ushort_t*)(wsb + (12u << 20));
  ushort_t* QDL  = (ushort_t*)(wsb + (14u << 20));
  ushort_t* Kb   = (ushort_t*)(wsb + (16u << 20));
  ushort_t* Vt   = (ushort_t*)(wsb + (20u << 20));
  ushort_t* Wsh  = (ushort_t*)(wsb + (22u << 20));
  ushort_t* Wsl  = (ushort_t*)(wsb + (23u << 20));
  ushort_t* Wosh = (ushort_t*)(wsb + (24u << 20));
  ushort_t* Wosl = (ushort_t*)(wsb + (25u << 20));
  ushort_t* HdH  = qh_g;   // dead after proj; stream-ordered reuse
  ushort_t* HdL  = ql_g;

  conv_kernel<<<dim3(512), 256, 0, stream>>>(q, Wq, Wk, Wv, W1, W2, W3, W4, Wo,
                                             qh_g, ql_g, Wsh, Wsl, Wosh, Wosl);
  proj_kernel<<<dim3(8, NB, NH), 256, 0, stream>>>(qh_g, ql_g, Wsh, Wsl,
                                                   QcH, QcL, QPH, QPL, QDH, QDL, Kb, Vt);
  attn_kernel<<<dim3(4, NB, NH), dim3(512), 0, stream>>>(QcH, QcL, QPH, QPL, QDH, QDL,
                                                         Kb, Vt, HdH, HdL);
  out_kernel<<<dim3(4, 16, NB), 256, 0, stream>>>(HdH, HdL, Wosh, Wosl, out);
}